// Round 4
// baseline (9203.925 us; speedup 1.0000x reference)
//
#include <hip/hip_runtime.h>

// LSTM T=32768, D=512, H=20.
// Phase 1: xg[t][80] = x[t] @ W_ih^T + (b_ih + b_hh)   (tiled fp32 GEMM)
// Phase 2: sequential scan, ONE wave:
//   lanes 0..19  : unit j, gates i (rowA=j)    and f (rowB=20+j)
//   lanes 32..51 : unit j, gates g (rowA=40+j) and o (rowB=60+j)
//   ROUND-4 CHANGE: no private arrays AT ALL in the scan — all 40 weights
//   and all 32 prefetch-ring slots are individually named scalars
//   (macro-generated), each weight laundered through asm so it cannot be
//   rematerialized/reloaded; waves_per_eu pinned to (1,1) to open the
//   full 512-VGPR budget. Rounds 1-3 all compiled to VGPR_Count=40..48,
//   i.e. weights/ring lived in L1/L2-resident memory and every step paid
//   ~40 loads + vmcnt waits in the dependent chain (~657 cy/step).
// Phase 3: out[t] = hs[t] @ W_out^T + b_out
//
// d_out layout: [0..T) outputs, [T..T+20) hT, [T+20..T+40) cT
// d_ws layout:  xg (T+16 rows x 80 fp32) then hs (T x 20 fp32)

#define TT 32768
#define DD 512
#define HH 20

__device__ __forceinline__ float ex2(float x) {
#if __has_builtin(__builtin_amdgcn_exp2f)
  return __builtin_amdgcn_exp2f(x);
#else
  return exp2f(x);
#endif
}
__device__ __forceinline__ float rcpa(float x) { return __builtin_amdgcn_rcpf(x); }
__device__ __forceinline__ float rlane(float v, int l) {
  return __int_as_float(__builtin_amdgcn_readlane(__float_as_int(v), l));
}

// ---------------- Phase 1: xg GEMM -------------------------------------
__global__ __launch_bounds__(256)
void xg_gemm(const float* __restrict__ x,    // (T, 512)
             const float* __restrict__ Wih,  // (80, 512)
             const float* __restrict__ bih,  // (80)
             const float* __restrict__ bhh,  // (80)
             float* __restrict__ xg)         // (T+16, 80)
{
  __shared__ float xa[64][68];
  __shared__ float wb[80][68];

  const int tid = threadIdx.x;
  const int t0  = blockIdx.x << 6;
  const int tt  = (tid & 15) << 2;
  const int gg  = (tid >> 4) * 5;

  float acc[4][5];
#pragma unroll
  for (int i = 0; i < 4; ++i)
#pragma unroll
    for (int q = 0; q < 5; ++q) acc[i][q] = 0.0f;

  for (int k0 = 0; k0 < DD; k0 += 64) {
#pragma unroll
    for (int i = 0; i < 4; ++i) {
      int id = tid + (i << 8);
      int r = id >> 4, c4 = (id & 15) << 2;
      *(float4*)&xa[r][c4] = *(const float4*)&x[(size_t)(t0 + r) * DD + k0 + c4];
    }
#pragma unroll
    for (int i = 0; i < 5; ++i) {
      int id = tid + (i << 8);
      int r = id >> 4, c4 = (id & 15) << 2;
      *(float4*)&wb[r][c4] = *(const float4*)&Wih[(size_t)r * DD + k0 + c4];
    }
    __syncthreads();

#pragma unroll 4
    for (int kk = 0; kk < 64; kk += 4) {
      float4 a[4], b[5];
#pragma unroll
      for (int i = 0; i < 4; ++i) a[i] = *(const float4*)&xa[tt + i][kk];
#pragma unroll
      for (int q = 0; q < 5; ++q) b[q] = *(const float4*)&wb[gg + q][kk];
#pragma unroll
      for (int i = 0; i < 4; ++i)
#pragma unroll
        for (int q = 0; q < 5; ++q) {
          acc[i][q] = fmaf(a[i].x, b[q].x, acc[i][q]);
          acc[i][q] = fmaf(a[i].y, b[q].y, acc[i][q]);
          acc[i][q] = fmaf(a[i].z, b[q].z, acc[i][q]);
          acc[i][q] = fmaf(a[i].w, b[q].w, acc[i][q]);
        }
    }
    __syncthreads();
  }

  float bg[5];
#pragma unroll
  for (int q = 0; q < 5; ++q) bg[q] = bih[gg + q] + bhh[gg + q];
#pragma unroll
  for (int i = 0; i < 4; ++i)
#pragma unroll
    for (int q = 0; q < 5; ++q)
      xg[(size_t)(t0 + tt + i) * 80 + gg + q] = acc[i][q] + bg[q];
}

// ---------------- Phase 2: sequential scan, one wave -------------------
__global__ __launch_bounds__(64)
__attribute__((amdgpu_waves_per_eu(1, 1)))
void lstm_scan(const float* __restrict__ xg,   // (T+16, 80)
               const float* __restrict__ Whh,  // (80, 20)
               const float* __restrict__ h0,   // (20)
               const float* __restrict__ c0,   // (20)
               float* __restrict__ hs,         // (T, 20)
               float* __restrict__ dout)       // d_out base (fp32)
{
  const int lane = threadIdx.x & 63;
  const int half = lane >> 5;
  int jj = lane & 31; if (jj > 19) jj = 19;
  const int rowA = half ? (40 + jj) : jj;   // i-row | g-row
  const int rowB = rowA + 20;               // f-row | o-row

  // ---- 40 weights as NAMED SCALARS (no arrays -> nothing can demote) ----
#define WDECL(K) float wA##K, wB##K;
  WDECL(0) WDECL(1) WDECL(2) WDECL(3) WDECL(4) WDECL(5) WDECL(6) WDECL(7)
  WDECL(8) WDECL(9) WDECL(10) WDECL(11) WDECL(12) WDECL(13) WDECL(14)
  WDECL(15) WDECL(16) WDECL(17) WDECL(18) WDECL(19)
#undef WDECL
  {
    const float4* ra = (const float4*)(Whh + rowA * HH);  // rows 80B-aligned
    const float4* rb = (const float4*)(Whh + rowB * HH);
    float4 v;
    v = ra[0]; wA0  = v.x; wA1  = v.y; wA2  = v.z; wA3  = v.w;
    v = ra[1]; wA4  = v.x; wA5  = v.y; wA6  = v.z; wA7  = v.w;
    v = ra[2]; wA8  = v.x; wA9  = v.y; wA10 = v.z; wA11 = v.w;
    v = ra[3]; wA12 = v.x; wA13 = v.y; wA14 = v.z; wA15 = v.w;
    v = ra[4]; wA16 = v.x; wA17 = v.y; wA18 = v.z; wA19 = v.w;
    v = rb[0]; wB0  = v.x; wB1  = v.y; wB2  = v.z; wB3  = v.w;
    v = rb[1]; wB4  = v.x; wB5  = v.y; wB6  = v.z; wB7  = v.w;
    v = rb[2]; wB8  = v.x; wB9  = v.y; wB10 = v.z; wB11 = v.w;
    v = rb[3]; wB12 = v.x; wB13 = v.y; wB14 = v.z; wB15 = v.w;
    v = rb[4]; wB16 = v.x; wB17 = v.y; wB18 = v.z; wB19 = v.w;
  }
  // launder: values now defined by opaque asm -> must stay in VGPRs
#define LAU(K) asm("" : "+v"(wA##K)); asm("" : "+v"(wB##K));
  LAU(0) LAU(1) LAU(2) LAU(3) LAU(4) LAU(5) LAU(6) LAU(7) LAU(8) LAU(9)
  LAU(10) LAU(11) LAU(12) LAU(13) LAU(14) LAU(15) LAU(16) LAU(17) LAU(18) LAU(19)
#undef LAU

  const float A0 = half ? -2.0f        : 1.0f;
  const float B0 = half ? 2.88539008f  : -1.44269504f;
  const float C0 = half ? 1.0f         : 0.0f;

  float h = h0[jj];
  float c = c0[jj];

  // ---- ping-pong prefetch rings as NAMED SCALARS ----
  float qA0,qA1,qA2,qA3,qA4,qA5,qA6,qA7, qB0,qB1,qB2,qB3,qB4,qB5,qB6,qB7;
  float sA0,sA1,sA2,sA3,sA4,sA5,sA6,sA7, sB0,sB1,sB2,sB3,sB4,sB5,sB6,sB7;
  const float* pa = xg + rowA;
  const float* pb = xg + rowB;

#define LDRING(P) \
    P##A0 = pa[0*80]; P##B0 = pb[0*80]; P##A1 = pa[1*80]; P##B1 = pb[1*80]; \
    P##A2 = pa[2*80]; P##B2 = pb[2*80]; P##A3 = pa[3*80]; P##B3 = pb[3*80]; \
    P##A4 = pa[4*80]; P##B4 = pb[4*80]; P##A5 = pa[5*80]; P##B5 = pb[5*80]; \
    P##A6 = pa[6*80]; P##B6 = pb[6*80]; P##A7 = pa[7*80]; P##B7 = pb[7*80]; \
    pa += 8*80; pb += 8*80;

  LDRING(q)   // rows 0..7; pa/pb now at row 8

  float* hsp = hs + jj;
  const bool live = (lane < HH);

#define MAC(K, A, B) { const float hk = rlane(h, K); \
    A = fmaf(hk, wA##K, A); B = fmaf(hk, wB##K, B); }

#define STEP(GA, GB, HSOFF) { \
    float a0 = GA, a1 = 0.f, a2 = 0.f, a3 = 0.f; \
    float b0 = GB, b1 = 0.f, b2 = 0.f, b3 = 0.f; \
    MAC( 0,a0,b0) MAC( 1,a1,b1) MAC( 2,a2,b2) MAC( 3,a3,b3) \
    MAC( 4,a0,b0) MAC( 5,a1,b1) MAC( 6,a2,b2) MAC( 7,a3,b3) \
    MAC( 8,a0,b0) MAC( 9,a1,b1) MAC(10,a2,b2) MAC(11,a3,b3) \
    MAC(12,a0,b0) MAC(13,a1,b1) MAC(14,a2,b2) MAC(15,a3,b3) \
    MAC(16,a0,b0) MAC(17,a1,b1) MAC(18,a2,b2) MAC(19,a3,b3) \
    const float gAs = (a0 + a1) + (a2 + a3); \
    const float gBs = (b0 + b1) + (b2 + b3); \
    const float vA = fmaf(A0, rcpa(1.0f + ex2(B0 * gAs)), C0); \
    const float vB = rcpa(1.0f + ex2(-1.44269504f * gBs)); \
    const float tg = __shfl(vA, (lane & 31) + 32); \
    const float so = __shfl(vB, (lane & 31) + 32); \
    c = fmaf(vB, c, vA * tg); \
    const float th = fmaf(-2.0f, rcpa(1.0f + ex2(2.88539008f * c)), 1.0f); \
    h = so * th; \
    if (live) hsp[(HSOFF) * HH] = h; \
  }

  for (int tb = 0; tb < TT; tb += 16) {
    LDRING(s)                         // rows tb+8 .. tb+15
    STEP(qA0, qB0, 0) STEP(qA1, qB1, 1)
    STEP(qA2, qB2, 2) STEP(qA3, qB3, 3)
    STEP(qA4, qB4, 4) STEP(qA5, qB5, 5)
    STEP(qA6, qB6, 6) STEP(qA7, qB7, 7)
    LDRING(q)                         // rows tb+16 .. tb+23 (xg padded to T+16)
    STEP(sA0, sB0,  8) STEP(sA1, sB1,  9)
    STEP(sA2, sB2, 10) STEP(sA3, sB3, 11)
    STEP(sA4, sB4, 12) STEP(sA5, sB5, 13)
    STEP(sA6, sB6, 14) STEP(sA7, sB7, 15)
    hsp += 16 * HH;
  }
#undef STEP
#undef MAC
#undef LDRING

  if (live) {
    dout[TT + lane] = h;         // hT
    dout[TT + HH + lane] = c;    // cT
  }
}

// ---------------- Phase 3: output projection ---------------------------
__global__ __launch_bounds__(256)
void proj(const float* __restrict__ hs,    // (T, 20)
          const float* __restrict__ Wout,  // (1, 20)
          const float* __restrict__ bout,  // (1)
          float* __restrict__ out)         // (T)
{
  const int t = blockIdx.x * 256 + threadIdx.x;
  const float4* hp = (const float4*)(hs + (size_t)t * HH);
  float acc = bout[0];
#pragma unroll
  for (int q = 0; q < 5; ++q) {
    float4 hv = hp[q];
    float4 wv = *(const float4*)&Wout[q * 4];
    acc = fmaf(hv.x, wv.x, acc);
    acc = fmaf(hv.y, wv.y, acc);
    acc = fmaf(hv.z, wv.z, acc);
    acc = fmaf(hv.w, wv.w, acc);
  }
  out[t] = acc;
}

extern "C" void kernel_launch(void* const* d_in, const int* in_sizes, int n_in,
                              void* d_out, int out_size, void* d_ws, size_t ws_size,
                              hipStream_t stream) {
  const float* x    = (const float*)d_in[0];
  const float* h0   = (const float*)d_in[1];
  const float* c0   = (const float*)d_in[2];
  const float* Wih  = (const float*)d_in[3];
  const float* Whh  = (const float*)d_in[4];
  const float* bih  = (const float*)d_in[5];
  const float* bhh  = (const float*)d_in[6];
  const float* Wout = (const float*)d_in[7];
  const float* bout = (const float*)d_in[8];
  float* out = (float*)d_out;

  float* xg = (float*)d_ws;                       // (T+16) x 80
  float* hs = xg + (size_t)(TT + 16) * 80;        // T x 20

  xg_gemm<<<dim3(TT / 64), dim3(256), 0, stream>>>(x, Wih, bih, bhh, xg);
  lstm_scan<<<dim3(1), dim3(64), 0, stream>>>(xg, Whh, h0, c0, hs, out);
  proj<<<dim3(TT / 256), dim3(256), 0, stream>>>(hs, Wout, bout, out);
}

// Round 7
// 6045.081 us; speedup vs baseline: 1.5225x; 1.5225x over previous
//
#include <hip/hip_runtime.h>

// LSTM T=32768, D=512, H=20.
// Phase 1: xg GEMM -> pre-scaled, pair-interleaved gate pre-activations.
//   col layout per t (80 floats): [i0,f0, i1,f1, ... i19,f19, g0,o0, ... g19,o19]
//   each value pre-multiplied by its activation's exp2 scale:
//     sigmoid rows (i,f,o): *-log2(e) = -1.44269504
//     tanh rows   (g)     : *+2*log2(e) = +2.88539008
// Phase 2: ONE-wave scan, instruction-count-minimized:
//   lanes 0..19: unit j rows (i_j, f_j); lanes 32..51: unit j rows (g_j, o_j)
//   - h pairs packed to f16x2 via DPP quad-perm + cvt_pkrtz (no LDS)
//   - 10 readlane + 20 v_dot2_f32_f16 replace 20 readlane + 40 v_fma
//   - cross-half exchange via v_permlane32_swap + XOR identity (round-7 fix:
//     r.x^r.y^x == x[lane^32] bit-exactly under EITHER swap orientation —
//     round 6 picked the wrong half and got own-half values)
//   - both halves keep valid c,h -> unmasked per-step store (no exec churn)
// Phase 3: out[t] = hs[t] @ W_out^T + b_out
//
// d_out: [0..T) outputs, [T..T+20) hT, [T+20..T+40) cT
// d_ws:  xg (T+16 rows x 80 fp32) then hs (T x 20 fp32)

#define TT 32768
#define DD 512
#define HH 20

typedef __fp16 h2 __attribute__((ext_vector_type(2)));   // matches builtin sigs
typedef unsigned int v2u __attribute__((ext_vector_type(2)));

__device__ __forceinline__ float ex2(float x) {
#if __has_builtin(__builtin_amdgcn_exp2f)
  return __builtin_amdgcn_exp2f(x);
#else
  return exp2f(x);
#endif
}
__device__ __forceinline__ float rcpa(float x) { return __builtin_amdgcn_rcpf(x); }

__device__ __forceinline__ int h22i(h2 h) { union { h2 h; int i; } u; u.h = h; return u.i; }
__device__ __forceinline__ h2 i2h2(int i) { union { int i; h2 h; } u; u.i = i; return u.h; }

__device__ __forceinline__ float dot2f(h2 a, h2 b, float c) {
#if __has_builtin(__builtin_amdgcn_fdot2)
  return __builtin_amdgcn_fdot2(a, b, c, false);
#else
  return fmaf((float)a.x, (float)b.x, fmaf((float)a.y, (float)b.y, c));
#endif
}

// neighbor-swap within quads (lane ^ 1) — pure VALU DPP, no LDS
__device__ __forceinline__ int dppswap1(int x) {
#if __has_builtin(__builtin_amdgcn_mov_dpp)
  return __builtin_amdgcn_mov_dpp(x, 0xB1, 0xF, 0xF, true);  // quad_perm [1,0,3,2]
#else
  return __float_as_int(__shfl_xor(__int_as_float(x), 1));
#endif
}

// full 32<->32 half-wave exchange, direction-proof:
// feed x to both swap operands; at every lane {r.x, r.y} == {x[lane], x[lane^32]}
// as bit patterns (in SOME order) => r.x ^ r.y ^ x == x[lane^32] exactly.
__device__ __forceinline__ float cross32(float x) {
#if __has_builtin(__builtin_amdgcn_permlane32_swap)
  const unsigned xb = (unsigned)__float_as_int(x);
  v2u r = __builtin_amdgcn_permlane32_swap(xb, xb, false, false);
  return __int_as_float((int)(r.x ^ r.y ^ xb));
#else
  return __shfl_xor(x, 32);
#endif
}

// ---------------- Phase 1: xg GEMM -------------------------------------
__global__ __launch_bounds__(256)
void xg_gemm(const float* __restrict__ x,    // (T, 512)
             const float* __restrict__ Wih,  // (80, 512)
             const float* __restrict__ bih,  // (80)
             const float* __restrict__ bhh,  // (80)
             float* __restrict__ xg)         // (T+16, 80) permuted+scaled
{
  __shared__ float xa[64][68];
  __shared__ float wb[80][68];

  const int tid = threadIdx.x;
  const int t0  = blockIdx.x << 6;
  const int tt  = (tid & 15) << 2;
  const int gg  = (tid >> 4) * 5;

  float acc[4][5];
#pragma unroll
  for (int i = 0; i < 4; ++i)
#pragma unroll
    for (int q = 0; q < 5; ++q) acc[i][q] = 0.0f;

  for (int k0 = 0; k0 < DD; k0 += 64) {
#pragma unroll
    for (int i = 0; i < 4; ++i) {
      int id = tid + (i << 8);
      int r = id >> 4, c4 = (id & 15) << 2;
      *(float4*)&xa[r][c4] = *(const float4*)&x[(size_t)(t0 + r) * DD + k0 + c4];
    }
#pragma unroll
    for (int i = 0; i < 5; ++i) {
      int id = tid + (i << 8);
      int r = id >> 4, c4 = (id & 15) << 2;
      *(float4*)&wb[r][c4] = *(const float4*)&Wih[(size_t)r * DD + k0 + c4];
    }
    __syncthreads();

#pragma unroll 4
    for (int kk = 0; kk < 64; kk += 4) {
      float4 a[4], b[5];
#pragma unroll
      for (int i = 0; i < 4; ++i) a[i] = *(const float4*)&xa[tt + i][kk];
#pragma unroll
      for (int q = 0; q < 5; ++q) b[q] = *(const float4*)&wb[gg + q][kk];
#pragma unroll
      for (int i = 0; i < 4; ++i)
#pragma unroll
        for (int q = 0; q < 5; ++q) {
          acc[i][q] = fmaf(a[i].x, b[q].x, acc[i][q]);
          acc[i][q] = fmaf(a[i].y, b[q].y, acc[i][q]);
          acc[i][q] = fmaf(a[i].z, b[q].z, acc[i][q]);
          acc[i][q] = fmaf(a[i].w, b[q].w, acc[i][q]);
        }
    }
    __syncthreads();
  }

  // epilogue: bias, activation pre-scale, pair-interleaved column permute
#pragma unroll
  for (int q = 0; q < 5; ++q) {
    const int r  = gg + q;            // gate row 0..79
    const int u  = r % 20;            // unit
    const int ty = r / 20;            // 0=i 1=f 2=g 3=o
    const int col = (ty & 2) * 20 + 2 * u + (ty & 1);
    const float sc = (ty == 2) ? 2.88539008f : -1.44269504f;
    const float bg = bih[r] + bhh[r];
#pragma unroll
    for (int i = 0; i < 4; ++i)
      xg[(size_t)(t0 + tt + i) * 80 + col] = (acc[i][q] + bg) * sc;
  }
}

// ---------------- Phase 2: sequential scan, one wave -------------------
__global__ __launch_bounds__(64)
__attribute__((amdgpu_waves_per_eu(1, 1)))
void lstm_scan(const float* __restrict__ xg,   // (T+16, 80) permuted+scaled
               const float* __restrict__ Whh,  // (80, 20)
               const float* __restrict__ h0,   // (20)
               const float* __restrict__ c0,   // (20)
               float* __restrict__ hs,         // (T, 20)
               float* __restrict__ dout)       // d_out base (fp32)
{
  const int lane = threadIdx.x & 63;
  const int hf   = lane >> 5;               // 0: rows i,f   1: rows g,o
  int jj = lane & 31; if (jj > 19) jj = 19; // spare lanes mirror unit 19
  const int rowA = hf ? (40 + jj) : jj;     // i | g
  const int rowB = rowA + 20;               // f | o

  // --- pack Whh rows to f16 pairs, pre-scaled by the activation constant ---
  const float sA = hf ? 2.88539008f : -1.44269504f;  // g: tanh scale, i: sigm
  const float sB = -1.44269504f;                      // f,o: sigmoid
  h2 wpa0,wpa1,wpa2,wpa3,wpa4,wpa5,wpa6,wpa7,wpa8,wpa9;
  h2 wpb0,wpb1,wpb2,wpb3,wpb4,wpb5,wpb6,wpb7,wpb8,wpb9;
  {
    const float2* ra = (const float2*)(Whh + rowA * HH);
    const float2* rb = (const float2*)(Whh + rowB * HH);
#define PKW(M) { float2 va = ra[M], vb = rb[M]; \
    wpa##M = __builtin_amdgcn_cvt_pkrtz(va.x * sA, va.y * sA); \
    wpb##M = __builtin_amdgcn_cvt_pkrtz(vb.x * sB, vb.y * sB); }
    PKW(0) PKW(1) PKW(2) PKW(3) PKW(4) PKW(5) PKW(6) PKW(7) PKW(8) PKW(9)
#undef PKW
  }

  const float A0 = hf ? -2.0f : 1.0f;
  const float C0 = hf ? 1.0f  : 0.0f;

  float h = h0[jj];
  float c = c0[jj];

  // --- ping-pong ring: 8 float2/phase, one dwordx2 per step ---
  float2 qr0,qr1,qr2,qr3,qr4,qr5,qr6,qr7;
  float2 sr0,sr1,sr2,sr3,sr4,sr5,sr6,sr7;
  const float2* pp = (const float2*)(xg + (hf ? 40 : 0)) + jj;  // stride 40 f2/row

#define LDRING(P) \
    P##0 = pp[0*40]; P##1 = pp[1*40]; P##2 = pp[2*40]; P##3 = pp[3*40]; \
    P##4 = pp[4*40]; P##5 = pp[5*40]; P##6 = pp[6*40]; P##7 = pp[7*40]; \
    pp += 8*40;

  LDRING(qr)   // rows 0..7; pp now at row 8

  float* hsp = hs + jj;

#define DMAC(M, A, B) { \
    const int hb = __builtin_amdgcn_readlane(hpi, 2*(M)); \
    const h2 hm = i2h2(hb); \
    A = dot2f(hm, wpa##M, A); B = dot2f(hm, wpb##M, B); }

#define STEP(G, HSOFF) { \
    const int hx = dppswap1(__float_as_int(h)); \
    const h2 hp = __builtin_amdgcn_cvt_pkrtz(h, __int_as_float(hx)); \
    const int hpi = h22i(hp); \
    float a0 = G.x, a1 = 0.f, b0 = G.y, b1 = 0.f; \
    DMAC(0,a0,b0) DMAC(1,a1,b1) DMAC(2,a0,b0) DMAC(3,a1,b1) DMAC(4,a0,b0) \
    DMAC(5,a1,b1) DMAC(6,a0,b0) DMAC(7,a1,b1) DMAC(8,a0,b0) DMAC(9,a1,b1) \
    const float gAs = a0 + a1; \
    const float gBs = b0 + b1; \
    const float vA = fmaf(A0, rcpa(1.0f + ex2(gAs)), C0); \
    const float vB = rcpa(1.0f + ex2(gBs)); \
    const float tgx = cross32(vA); \
    const float sox = cross32(vB); \
    const float fsel = hf ? sox : vB;   /* sigma(f) in both halves */ \
    const float osel = hf ? vB : sox;   /* sigma(o) in both halves */ \
    c = fmaf(fsel, c, vA * tgx);        /* vA*tgx = sigma(i)*tanh(g) */ \
    const float th = fmaf(-2.0f, rcpa(1.0f + ex2(2.88539008f * c)), 1.0f); \
    h = osel * th; \
    hsp[(HSOFF) * HH] = h;              /* all 64 lanes: dup addr, dup value */ \
  }

  for (int tb = 0; tb < TT; tb += 16) {
    LDRING(sr)                          // rows tb+8 .. tb+15
    STEP(qr0, 0) STEP(qr1, 1) STEP(qr2, 2) STEP(qr3, 3)
    STEP(qr4, 4) STEP(qr5, 5) STEP(qr6, 6) STEP(qr7, 7)
    LDRING(qr)                          // rows tb+16.. (xg padded to T+16)
    STEP(sr0,  8) STEP(sr1,  9) STEP(sr2, 10) STEP(sr3, 11)
    STEP(sr4, 12) STEP(sr5, 13) STEP(sr6, 14) STEP(sr7, 15)
    hsp += 16 * HH;
  }
#undef STEP
#undef DMAC
#undef LDRING

  if (lane < HH) {
    dout[TT + lane] = h;         // hT
    dout[TT + HH + lane] = c;    // cT
  }
}

// ---------------- Phase 3: output projection ---------------------------
__global__ __launch_bounds__(256)
void proj(const float* __restrict__ hs,    // (T, 20)
          const float* __restrict__ Wout,  // (1, 20)
          const float* __restrict__ bout,  // (1)
          float* __restrict__ out)         // (T)
{
  const int t = blockIdx.x * 256 + threadIdx.x;
  const float4* hp = (const float4*)(hs + (size_t)t * HH);
  float acc = bout[0];
#pragma unroll
  for (int q = 0; q < 5; ++q) {
    float4 hv = hp[q];
    float4 wv = *(const float4*)&Wout[q * 4];
    acc = fmaf(hv.x, wv.x, acc);
    acc = fmaf(hv.y, wv.y, acc);
    acc = fmaf(hv.z, wv.z, acc);
    acc = fmaf(hv.w, wv.w, acc);
  }
  out[t] = acc;
}

extern "C" void kernel_launch(void* const* d_in, const int* in_sizes, int n_in,
                              void* d_out, int out_size, void* d_ws, size_t ws_size,
                              hipStream_t stream) {
  const float* x    = (const float*)d_in[0];
  const float* h0   = (const float*)d_in[1];
  const float* c0   = (const float*)d_in[2];
  const float* Wih  = (const float*)d_in[3];
  const float* Whh  = (const float*)d_in[4];
  const float* bih  = (const float*)d_in[5];
  const float* bhh  = (const float*)d_in[6];
  const float* Wout = (const float*)d_in[7];
  const float* bout = (const float*)d_in[8];
  float* out = (float*)d_out;

  float* xg = (float*)d_ws;                       // (T+16) x 80
  float* hs = xg + (size_t)(TT + 16) * 80;        // T x 20

  xg_gemm<<<dim3(TT / 64), dim3(256), 0, stream>>>(x, Wih, bih, bhh, xg);
  lstm_scan<<<dim3(1), dim3(64), 0, stream>>>(xg, Whh, h0, c0, hs, out);
  proj<<<dim3(TT / 256), dim3(256), 0, stream>>>(hs, Wout, bout, out);
}